// Round 2
// baseline (2497.390 us; speedup 1.0000x reference)
//
#include <hip/hip_runtime.h>
#include <hip/hip_fp16.h>
#include <cmath>

typedef _Float16 f16;
typedef f16 f16x8 __attribute__((ext_vector_type(8)));
typedef float f32x4 __attribute__((ext_vector_type(4)));

#define T_TOK 4096
#define DIM   2048
#define SEQ   2048
#define NHEAD 16
#define NKVH  4
#define HDIM  128
#define NEXP  8
#define FDIM  1408
#define RMS_EPS 1e-6f
#define NQ    2048   // NH*HD
#define NKVD  512    // NKV*HD

#define MFMA16(A,B,C) __builtin_amdgcn_mfma_f32_16x16x32_f16(A,B,C,0,0,0)

__device__ __forceinline__ void fsplit(float x, f16 &h, f16 &l) {
  f16 hh = (f16)x; h = hh; l = (f16)(x - (float)hh);
}

// ---------------- fused add-residual + RMSNorm (writes res + hi/lo f16 normed) ----------------
__global__ __launch_bounds__(256) void k_rmsnorm1(
    const float* __restrict__ hid, const float* __restrict__ resi,
    const float* __restrict__ w, float* __restrict__ res_out,
    f16* __restrict__ nh, f16* __restrict__ nl) {
  int row = blockIdx.x, tid = threadIdx.x;
  size_t base = (size_t)row * DIM + tid * 8;
  float4 a0 = *(const float4*)(hid + base);
  float4 a1 = *(const float4*)(hid + base + 4);
  float4 b0 = *(const float4*)(resi + base);
  float4 b1 = *(const float4*)(resi + base + 4);
  float v[8] = {a0.x+b0.x, a0.y+b0.y, a0.z+b0.z, a0.w+b0.w,
                a1.x+b1.x, a1.y+b1.y, a1.z+b1.z, a1.w+b1.w};
  float4 r0 = {v[0],v[1],v[2],v[3]}, r1 = {v[4],v[5],v[6],v[7]};
  *(float4*)(res_out + base) = r0;
  *(float4*)(res_out + base + 4) = r1;
  float ss = 0.f;
  #pragma unroll
  for (int j=0;j<8;++j) ss += v[j]*v[j];
  #pragma unroll
  for (int off=32; off>0; off>>=1) ss += __shfl_xor(ss, off);
  __shared__ float red[4];
  if ((tid & 63) == 0) red[tid>>6] = ss;
  __syncthreads();
  ss = red[0]+red[1]+red[2]+red[3];
  float scale = 1.0f / sqrtf(ss * (1.0f/DIM) + RMS_EPS);
  f16x8 oh, ol;
  #pragma unroll
  for (int j=0;j<8;++j) {
    float n = v[j] * scale * w[tid*8+j];
    f16 hh, ll; fsplit(n, hh, ll);
    oh[j] = hh; ol[j] = ll;
  }
  *(f16x8*)(nh + base) = oh;
  *(f16x8*)(nl + base) = ol;
}

// ---------------- split-f16 3-term GEMM: C = (Ah+Al)(Bh+Bl) approx, B from f32 ----------------
// MODE 0: C = A@B (store f32).  MODE 1: C += A@B (read-modify-write, C holds residual).
template<int MODE>
__global__ __launch_bounds__(256) void k_gemm_s3(
    const f16* __restrict__ Ah, const f16* __restrict__ Al, int lda,
    const float* __restrict__ B, int ldb,
    float* __restrict__ C, int ldc, int K) {
  __shared__ f16 sAh[128][40], sAl[128][40], sBh[128][40], sBl[128][40];
  int tid = threadIdx.x, l = tid & 63, wvi = tid >> 6;
  int wr = (wvi >> 1) * 64, wc = (wvi & 1) * 64;
  int m0 = blockIdx.y * 128, n0 = blockIdx.x * 128;
  int lh = l & 15, kg = (l >> 4) * 8;
  f32x4 zero4 = {0.f,0.f,0.f,0.f};
  f32x4 acc[4][4];
  #pragma unroll
  for (int mi=0;mi<4;++mi)
    #pragma unroll
    for (int ni=0;ni<4;++ni) acc[mi][ni] = zero4;
  int ar = tid >> 1, ac = (tid & 1) * 16;
  int bk = tid >> 3, bn = (tid & 7) * 16;
  const f16* gAh = Ah + (size_t)(m0 + ar) * lda + ac;
  const f16* gAl = Al + (size_t)(m0 + ar) * lda + ac;
  const float* gB0 = B + (size_t)bk * ldb + n0 + bn;
  for (int kt = 0; kt < K; kt += 32) {
    __syncthreads();
    *(f16x8*)&sAh[ar][ac]   = *(const f16x8*)(gAh + kt);
    *(f16x8*)&sAh[ar][ac+8] = *(const f16x8*)(gAh + kt + 8);
    *(f16x8*)&sAl[ar][ac]   = *(const f16x8*)(gAl + kt);
    *(f16x8*)&sAl[ar][ac+8] = *(const f16x8*)(gAl + kt + 8);
    const float* gb = gB0 + (size_t)kt * ldb;
    float xv[16];
    *(float4*)&xv[0]  = *(const float4*)(gb);
    *(float4*)&xv[4]  = *(const float4*)(gb+4);
    *(float4*)&xv[8]  = *(const float4*)(gb+8);
    *(float4*)&xv[12] = *(const float4*)(gb+12);
    #pragma unroll
    for (int i=0;i<16;++i) {
      f16 hh, ll; fsplit(xv[i], hh, ll);
      sBh[bn+i][bk] = hh; sBl[bn+i][bk] = ll;
    }
    __syncthreads();
    f16x8 fah[4], fal[4], fbh[4], fbl[4];
    #pragma unroll
    for (int mi=0;mi<4;++mi) {
      fah[mi] = *(const f16x8*)&sAh[wr + mi*16 + lh][kg];
      fal[mi] = *(const f16x8*)&sAl[wr + mi*16 + lh][kg];
    }
    #pragma unroll
    for (int ni=0;ni<4;++ni) {
      fbh[ni] = *(const f16x8*)&sBh[wc + ni*16 + lh][kg];
      fbl[ni] = *(const f16x8*)&sBl[wc + ni*16 + lh][kg];
    }
    #pragma unroll
    for (int mi=0;mi<4;++mi)
      #pragma unroll
      for (int ni=0;ni<4;++ni) {
        acc[mi][ni] = MFMA16(fal[mi], fbh[ni], acc[mi][ni]);
        acc[mi][ni] = MFMA16(fah[mi], fbl[ni], acc[mi][ni]);
        acc[mi][ni] = MFMA16(fah[mi], fbh[ni], acc[mi][ni]);
      }
  }
  int rg = (l >> 4) * 4;
  #pragma unroll
  for (int mi=0;mi<4;++mi)
    #pragma unroll
    for (int ni=0;ni<4;++ni) {
      int col = n0 + wc + ni*16 + lh;
      #pragma unroll
      for (int j=0;j<4;++j) {
        int row = m0 + wr + mi*16 + rg + j;
        float c = acc[mi][ni][j];
        float* p = C + (size_t)row * ldc + col;
        if (MODE == 1) c += *p;
        *p = c;
      }
    }
}

// ---------------- RoPE on q,k (f32 in, hi/lo f16 out) ----------------
__global__ __launch_bounds__(256) void k_rope(
    const float* __restrict__ qkvf, const float* __restrict__ cb, const float* __restrict__ sb,
    f16* __restrict__ qh, f16* __restrict__ ql, f16* __restrict__ kh, f16* __restrict__ kl) {
  int t = blockIdx.x;
  for (int p = threadIdx.x; p < 1280; p += 256) {
    bool isq = p < 1024;
    int pp = isq ? p : p - 1024;
    int hd = pp >> 6;
    int d = pp & 63;
    int col = hd * 128 + d;
    const float* src = qkvf + (size_t)t * 3072 + (isq ? 0 : 2048);
    float x1 = src[col], x2 = src[col + 64];
    float c = cb[(size_t)t*64 + d], s = sb[(size_t)t*64 + d];
    float o1 = x1*c - x2*s;
    float o2 = x2*c + x1*s;
    f16 h1,l1,h2,l2;
    fsplit(o1,h1,l1); fsplit(o2,h2,l2);
    if (isq) {
      size_t o = (size_t)t*NQ + col;
      qh[o]=h1; ql[o]=l1; qh[o+64]=h2; ql[o+64]=l2;
    } else {
      size_t o = (size_t)t*NKVD + col;
      kh[o]=h1; kl[o]=l1; kh[o+64]=h2; kl[o+64]=l2;
    }
  }
}

// ---------------- split v (f32 -> hi/lo f16) ----------------
__global__ __launch_bounds__(256) void k_split_v(
    const float* __restrict__ qkvf, f16* __restrict__ vh, f16* __restrict__ vl) {
  size_t i = ((size_t)blockIdx.x*256 + threadIdx.x) * 8;
  size_t t = i >> 9; int c = (int)(i & 511);
  const float* src = qkvf + t*3072 + 2560 + c;
  float4 x0 = *(const float4*)src, x1 = *(const float4*)(src+4);
  float xv[8] = {x0.x,x0.y,x0.z,x0.w,x1.x,x1.y,x1.z,x1.w};
  f16x8 hh, ll;
  #pragma unroll
  for (int j=0;j<8;++j) { f16 a,b2; fsplit(xv[j],a,b2); hh[j]=a; ll[j]=b2; }
  *(f16x8*)(vh + i) = hh;
  *(f16x8*)(vl + i) = ll;
}

// ---------------- flash attention, causal GQA, split-f16 3-term ----------------
__global__ __launch_bounds__(256) void k_attn(
    const f16* __restrict__ qh_, const f16* __restrict__ ql_,
    const f16* __restrict__ kh_, const f16* __restrict__ kl_,
    const f16* __restrict__ vh_, const f16* __restrict__ vl_,
    f16* __restrict__ oh_, f16* __restrict__ ol_) {
  __shared__ f16 sKh[32][136], sKl[32][136];
  __shared__ f16 sVh[128][40], sVl[128][40];
  __shared__ f16 sPh[4][16][40], sPl[4][16][40];
  int tid = threadIdx.x, l = tid&63, wvi = tid>>6;
  int qblk = blockIdx.x, h = blockIdx.y, b = blockIdx.z;
  int hk = h >> 2;
  int lh = l & 15, kg = (l>>4)*8;
  int qrow = qblk*64 + wvi*16 + lh;
  size_t qo = ((size_t)(b*SEQ + qrow))*NQ + h*HDIM;
  f16x8 Qh[4], Ql[4];
  #pragma unroll
  for (int f=0; f<4; ++f) {
    Qh[f] = *(const f16x8*)(qh_ + qo + f*32 + kg);
    Ql[f] = *(const f16x8*)(ql_ + qo + f*32 + kg);
  }
  f32x4 zero4 = {0.f,0.f,0.f,0.f};
  f32x4 oacc[8];
  #pragma unroll
  for (int df=0; df<8; ++df) oacc[df] = zero4;
  float m[4] = {-INFINITY,-INFINITY,-INFINITY,-INFINITY};
  float lsum[4] = {0.f,0.f,0.f,0.f};
  const float SCALE = 0.088388347648318447f;
  int sr = tid>>3, sd = (tid&7)*16;
  int ntiles = 2*qblk + 2;
  int qbase = qblk*64 + wvi*16 + (l>>4)*4;
  for (int kt=0; kt<ntiles; ++kt) {
    int kv0 = kt*32;
    __syncthreads();
    {
      size_t go = ((size_t)(b*SEQ + kv0 + sr))*NKVD + hk*HDIM + sd;
      *(f16x8*)&sKh[sr][sd]   = *(const f16x8*)(kh_+go);
      *(f16x8*)&sKh[sr][sd+8] = *(const f16x8*)(kh_+go+8);
      *(f16x8*)&sKl[sr][sd]   = *(const f16x8*)(kl_+go);
      *(f16x8*)&sKl[sr][sd+8] = *(const f16x8*)(kl_+go+8);
      f16x8 va = *(const f16x8*)(vh_+go), vb = *(const f16x8*)(vh_+go+8);
      f16x8 vc = *(const f16x8*)(vl_+go), vd = *(const f16x8*)(vl_+go+8);
      #pragma unroll
      for (int i=0;i<8;++i) {
        sVh[sd+i][sr] = va[i]; sVh[sd+8+i][sr] = vb[i];
        sVl[sd+i][sr] = vc[i]; sVl[sd+8+i][sr] = vd[i];
      }
    }
    __syncthreads();
    f32x4 sc[2]; sc[0]=zero4; sc[1]=zero4;
    #pragma unroll
    for (int cf=0; cf<2; ++cf) {
      #pragma unroll
      for (int ks=0; ks<4; ++ks) {
        f16x8 kfh = *(const f16x8*)&sKh[cf*16 + lh][ks*32 + kg];
        f16x8 kfl = *(const f16x8*)&sKl[cf*16 + lh][ks*32 + kg];
        sc[cf] = MFMA16(Ql[ks], kfh, sc[cf]);
        sc[cf] = MFMA16(Qh[ks], kfl, sc[cf]);
        sc[cf] = MFMA16(Qh[ks], kfh, sc[cf]);
      }
    }
    float mt[4] = {-INFINITY,-INFINITY,-INFINITY,-INFINITY};
    #pragma unroll
    for (int cf=0; cf<2; ++cf) {
      int kvc = kv0 + cf*16 + lh;
      #pragma unroll
      for (int j=0;j<4;++j) {
        float s = sc[cf][j] * SCALE;
        if (kvc > qbase + j) s = -INFINITY;
        sc[cf][j] = s;
        mt[j] = fmaxf(mt[j], s);
      }
    }
    #pragma unroll
    for (int off=8; off>0; off>>=1)
      #pragma unroll
      for (int j=0;j<4;++j) mt[j] = fmaxf(mt[j], __shfl_xor(mt[j], off));
    float fac[4], rs[4];
    #pragma unroll
    for (int j=0;j<4;++j) {
      float mn = fmaxf(m[j], mt[j]);
      fac[j] = expf(m[j] - mn);
      m[j] = mn;
      rs[j] = 0.f;
    }
    #pragma unroll
    for (int cf=0; cf<2; ++cf)
      #pragma unroll
      for (int j=0;j<4;++j) {
        float p = expf(sc[cf][j] - m[j]);
        rs[j] += p;
        f16 ph, pl; fsplit(p, ph, pl);
        sPh[wvi][(l>>4)*4 + j][cf*16 + lh] = ph;
        sPl[wvi][(l>>4)*4 + j][cf*16 + lh] = pl;
      }
    #pragma unroll
    for (int off=8; off>0; off>>=1)
      #pragma unroll
      for (int j=0;j<4;++j) rs[j] += __shfl_xor(rs[j], off);
    #pragma unroll
    for (int j=0;j<4;++j) lsum[j] = lsum[j]*fac[j] + rs[j];
    #pragma unroll
    for (int df=0; df<8; ++df) {
      oacc[df][0]*=fac[0]; oacc[df][1]*=fac[1];
      oacc[df][2]*=fac[2]; oacc[df][3]*=fac[3];
    }
    __syncthreads();
    f16x8 pah = *(const f16x8*)&sPh[wvi][lh][kg];
    f16x8 pal = *(const f16x8*)&sPl[wvi][lh][kg];
    #pragma unroll
    for (int df=0; df<8; ++df) {
      f16x8 vfh = *(const f16x8*)&sVh[df*16 + lh][kg];
      f16x8 vfl = *(const f16x8*)&sVl[df*16 + lh][kg];
      oacc[df] = MFMA16(pal, vfh, oacc[df]);
      oacc[df] = MFMA16(pah, vfl, oacc[df]);
      oacc[df] = MFMA16(pah, vfh, oacc[df]);
    }
  }
  float inv[4];
  #pragma unroll
  for (int j=0;j<4;++j) inv[j] = 1.0f / lsum[j];
  #pragma unroll
  for (int df=0; df<8; ++df)
    #pragma unroll
    for (int j=0;j<4;++j) {
      float o = oacc[df][j] * inv[j];
      size_t oo = ((size_t)(b*SEQ + qbase + j))*NQ + h*HDIM + df*16 + lh;
      f16 hh, ll; fsplit(o, hh, ll);
      oh_[oo] = hh; ol_[oo] = ll;
    }
}

// ---------------- RMSNorm2 + router (f32 logits, top-2) ----------------
__global__ __launch_bounds__(256) void k_rms2_router(
    const float* __restrict__ resin, const float* __restrict__ w,
    const float* __restrict__ rw, f16* __restrict__ n2,
    int* __restrict__ topi, float* __restrict__ topw) {
  int row = blockIdx.x, tid = threadIdx.x;
  size_t base = (size_t)row*DIM + tid*8;
  float4 a0 = *(const float4*)(resin + base);
  float4 a1 = *(const float4*)(resin + base + 4);
  float v[8] = {a0.x,a0.y,a0.z,a0.w,a1.x,a1.y,a1.z,a1.w};
  float ss = 0.f;
  #pragma unroll
  for (int j=0;j<8;++j) ss += v[j]*v[j];
  #pragma unroll
  for (int off=32; off>0; off>>=1) ss += __shfl_xor(ss, off);
  __shared__ float red[4];
  __shared__ float lsum2[4][8];
  if ((tid & 63) == 0) red[tid>>6] = ss;
  __syncthreads();
  ss = red[0]+red[1]+red[2]+red[3];
  float scale = 1.0f / sqrtf(ss * (1.0f/DIM) + RMS_EPS);
  float lg[8] = {0,0,0,0,0,0,0,0};
  f16x8 ov;
  #pragma unroll
  for (int j=0;j<8;++j) {
    float n = v[j] * scale * w[tid*8+j];
    ov[j] = (f16)n;
    const float* rwp = rw + (size_t)(tid*8+j)*8;
    float4 r0 = *(const float4*)rwp, r1 = *(const float4*)(rwp+4);
    lg[0]+=n*r0.x; lg[1]+=n*r0.y; lg[2]+=n*r0.z; lg[3]+=n*r0.w;
    lg[4]+=n*r1.x; lg[5]+=n*r1.y; lg[6]+=n*r1.z; lg[7]+=n*r1.w;
  }
  *(f16x8*)(n2 + base) = ov;
  #pragma unroll
  for (int e=0;e<8;++e)
    #pragma unroll
    for (int off=32; off>0; off>>=1) lg[e] += __shfl_xor(lg[e], off);
  if ((tid & 63) == 0)
    #pragma unroll
    for (int e=0;e<8;++e) lsum2[tid>>6][e] = lg[e];
  __syncthreads();
  if (tid == 0) {
    float L[8];
    #pragma unroll
    for (int e=0;e<8;++e) L[e] = lsum2[0][e]+lsum2[1][e]+lsum2[2][e]+lsum2[3][e];
    int i1 = 0;
    for (int e=1;e<8;++e) if (L[e] > L[i1]) i1 = e;
    int i2 = (i1==0) ? 1 : 0;
    for (int e=0;e<8;++e) if (e != i1 && L[e] > L[i2]) i2 = e;
    float e2 = expf(L[i2]-L[i1]);
    float s12 = 1.f + e2;
    topi[row*2] = i1; topi[row*2+1] = i2;
    topw[row*2] = 1.f/s12; topw[row*2+1] = e2/s12;
  }
}

// ---------------- expert counting / offsets / scatter ----------------
__global__ __launch_bounds__(256) void k_count(
    const int* __restrict__ topi, int* __restrict__ cnt,
    int* __restrict__ offs, int* __restrict__ fill) {
  __shared__ int c[NEXP];
  int tid = threadIdx.x;
  if (tid < NEXP) c[tid] = 0;
  __syncthreads();
  for (int i = tid; i < 2*T_TOK; i += 256) atomicAdd(&c[topi[i]], 1);
  __syncthreads();
  if (tid == 0) {
    int s = 0;
    for (int e=0; e<NEXP; ++e) { offs[e] = s; cnt[e] = c[e]; s += c[e]; }
    offs[NEXP] = s;
  }
  if (tid < NEXP) fill[tid] = 0;
}

__global__ __launch_bounds__(256) void k_scatter(
    const int* __restrict__ topi, const float* __restrict__ topw,
    const int* __restrict__ offs, int* __restrict__ fill,
    int* __restrict__ toks, float* __restrict__ wslot) {
  int i = blockIdx.x*256 + threadIdx.x;
  if (i >= 2*T_TOK) return;
  int e = topi[i];
  int pos = atomicAdd(&fill[e], 1);
  int sl = offs[e] + pos;
  toks[sl] = i >> 1;
  wslot[sl] = topw[i];
}

// ---------------- MoE up (fused gate+up, SiLU, f16 single) ----------------
__global__ __launch_bounds__(256) void k_moe_up(
    const f16* __restrict__ A, const float* __restrict__ w1, const float* __restrict__ w3,
    const int* __restrict__ cnt, const int* __restrict__ offs, const int* __restrict__ toks,
    f16* __restrict__ H) {
  int e = blockIdx.z;
  int ne = cnt[e];
  int m0 = blockIdx.y * 128;
  if (m0 >= ne) return;
  int goff = offs[e];
  int n0 = blockIdx.x * 128;
  const float* B1 = w1 + (size_t)e * DIM * FDIM;
  const float* B3 = w3 + (size_t)e * DIM * FDIM;
  __shared__ f16 sA[128][40], sB1[128][40], sB3[128][40];
  int tid=threadIdx.x, l=tid&63, wvi=tid>>6;
  int wr=(wvi>>1)*64, wc=(wvi&1)*64, lh=l&15, kg=(l>>4)*8;
  f32x4 zero4 = {0.f,0.f,0.f,0.f};
  f32x4 accg[4][4], accu[4][4];
  #pragma unroll
  for (int mi=0;mi<4;++mi)
    #pragma unroll
    for (int ni=0;ni<4;++ni) { accg[mi][ni]=zero4; accu[mi][ni]=zero4; }
  int ar = tid>>1, ac=(tid&1)*16;
  bool av = (m0 + ar) < ne;
  int tok = av ? toks[goff + m0 + ar] : 0;
  const f16* gA = A + (size_t)tok * DIM + ac;
  int bk = tid>>3, bn=(tid&7)*16;
  f16x8 zf = {(f16)0,(f16)0,(f16)0,(f16)0,(f16)0,(f16)0,(f16)0,(f16)0};
  for (int kt=0; kt<DIM; kt+=32) {
    __syncthreads();
    f16x8 x0 = av ? *(const f16x8*)(gA+kt) : zf;
    f16x8 x1 = av ? *(const f16x8*)(gA+kt+8) : zf;
    *(f16x8*)&sA[ar][ac] = x0; *(f16x8*)&sA[ar][ac+8] = x1;
    const float* g1 = B1 + (size_t)(kt+bk)*FDIM + n0 + bn;
    const float* g3 = B3 + (size_t)(kt+bk)*FDIM + n0 + bn;
    float y1[16], y3[16];
    *(float4*)&y1[0]=*(const float4*)(g1);   *(float4*)&y1[4]=*(const float4*)(g1+4);
    *(float4*)&y1[8]=*(const float4*)(g1+8); *(float4*)&y1[12]=*(const float4*)(g1+12);
    *(float4*)&y3[0]=*(const float4*)(g3);   *(float4*)&y3[4]=*(const float4*)(g3+4);
    *(float4*)&y3[8]=*(const float4*)(g3+8); *(float4*)&y3[12]=*(const float4*)(g3+12);
    #pragma unroll
    for (int i=0;i<16;++i) { sB1[bn+i][bk] = (f16)y1[i]; sB3[bn+i][bk] = (f16)y3[i]; }
    __syncthreads();
    f16x8 fa[4], f1[4], f3[4];
    #pragma unroll
    for (int mi=0;mi<4;++mi) fa[mi] = *(const f16x8*)&sA[wr+mi*16+lh][kg];
    #pragma unroll
    for (int ni=0;ni<4;++ni) {
      f1[ni] = *(const f16x8*)&sB1[wc+ni*16+lh][kg];
      f3[ni] = *(const f16x8*)&sB3[wc+ni*16+lh][kg];
    }
    #pragma unroll
    for (int mi=0;mi<4;++mi)
      #pragma unroll
      for (int ni=0;ni<4;++ni) {
        accg[mi][ni] = MFMA16(fa[mi], f1[ni], accg[mi][ni]);
        accu[mi][ni] = MFMA16(fa[mi], f3[ni], accu[mi][ni]);
      }
  }
  int rg=(l>>4)*4;
  #pragma unroll
  for (int mi=0;mi<4;++mi)
    #pragma unroll
    for (int ni=0;ni<4;++ni) {
      int col = n0 + wc + ni*16 + lh;
      #pragma unroll
      for (int j=0;j<4;++j) {
        int sl = m0 + wr + mi*16 + rg + j;
        if (sl < ne) {
          float g = accg[mi][ni][j], u = accu[mi][ni][j];
          float hv = g / (1.f + expf(-g)) * u;
          H[(size_t)(goff + sl)*FDIM + col] = (f16)hv;
        }
      }
    }
}

// ---------------- MoE down (f16 single, scatter-add with combine weight) ----------------
__global__ __launch_bounds__(256) void k_moe_down(
    const f16* __restrict__ H, const float* __restrict__ w2,
    const int* __restrict__ cnt, const int* __restrict__ offs,
    const int* __restrict__ toks, const float* __restrict__ wslot,
    float* __restrict__ out) {
  int e = blockIdx.z; int ne = cnt[e];
  int m0 = blockIdx.y*128; if (m0>=ne) return;
  int goff = offs[e]; int n0 = blockIdx.x*128;
  const float* B = w2 + (size_t)e*FDIM*DIM;
  __shared__ f16 sA[128][40], sB[128][40];
  int tid=threadIdx.x, l=tid&63, wvi=tid>>6;
  int wr=(wvi>>1)*64, wc=(wvi&1)*64, lh=l&15, kg=(l>>4)*8;
  f32x4 zero4 = {0.f,0.f,0.f,0.f};
  f32x4 acc[4][4];
  #pragma unroll
  for (int mi=0;mi<4;++mi)
    #pragma unroll
    for (int ni=0;ni<4;++ni) acc[mi][ni]=zero4;
  int ar = tid>>1, ac=(tid&1)*16;
  bool av = (m0 + ar) < ne;
  const f16* gA = H + (size_t)(goff + m0 + ar)*FDIM + ac;
  int bk = tid>>3, bn=(tid&7)*16;
  f16x8 zf = {(f16)0,(f16)0,(f16)0,(f16)0,(f16)0,(f16)0,(f16)0,(f16)0};
  for (int kt=0; kt<FDIM; kt+=32) {
    __syncthreads();
    f16x8 x0 = av ? *(const f16x8*)(gA+kt) : zf;
    f16x8 x1 = av ? *(const f16x8*)(gA+kt+8) : zf;
    *(f16x8*)&sA[ar][ac] = x0; *(f16x8*)&sA[ar][ac+8] = x1;
    const float* gb = B + (size_t)(kt+bk)*DIM + n0 + bn;
    float yv[16];
    *(float4*)&yv[0]=*(const float4*)(gb);   *(float4*)&yv[4]=*(const float4*)(gb+4);
    *(float4*)&yv[8]=*(const float4*)(gb+8); *(float4*)&yv[12]=*(const float4*)(gb+12);
    #pragma unroll
    for (int i=0;i<16;++i) sB[bn+i][bk] = (f16)yv[i];
    __syncthreads();
    f16x8 fa[4], fb[4];
    #pragma unroll
    for (int mi=0;mi<4;++mi) fa[mi] = *(const f16x8*)&sA[wr+mi*16+lh][kg];
    #pragma unroll
    for (int ni=0;ni<4;++ni) fb[ni] = *(const f16x8*)&sB[wc+ni*16+lh][kg];
    #pragma unroll
    for (int mi=0;mi<4;++mi)
      #pragma unroll
      for (int ni=0;ni<4;++ni) acc[mi][ni] = MFMA16(fa[mi], fb[ni], acc[mi][ni]);
  }
  int rg=(l>>4)*4;
  #pragma unroll
  for (int mi=0;mi<4;++mi)
    #pragma unroll
    for (int ni=0;ni<4;++ni) {
      int col = n0 + wc + ni*16 + lh;
      #pragma unroll
      for (int j=0;j<4;++j) {
        int sl = m0 + wr + mi*16 + rg + j;
        if (sl < ne) {
          int tk = toks[goff+sl];
          float wcmb = wslot[goff+sl];
          atomicAdd(out + (size_t)tk*DIM + col, wcmb*acc[mi][ni][j]);
        }
      }
    }
}

extern "C" void kernel_launch(void* const* d_in, const int* in_sizes, int n_in,
                              void* d_out, int out_size, void* d_ws, size_t ws_size,
                              hipStream_t stream) {
  (void)in_sizes; (void)n_in; (void)out_size; (void)ws_size;
  const float* hid  = (const float*)d_in[0];
  const float* resi = (const float*)d_in[1];
  const float* cosb = (const float*)d_in[2];
  const float* sinb = (const float*)d_in[3];
  const float* ln1  = (const float*)d_in[4];
  const float* ln2  = (const float*)d_in[5];
  const float* wq   = (const float*)d_in[6];
  const float* wk   = (const float*)d_in[7];
  const float* wv   = (const float*)d_in[8];
  const float* wo   = (const float*)d_in[9];
  const float* rw   = (const float*)d_in[10];
  const float* w1   = (const float*)d_in[11];
  const float* w3   = (const float*)d_in[12];
  const float* w2   = (const float*)d_in[13];
  float* out1 = (float*)d_out;
  float* resbuf = out1 + (size_t)T_TOK*DIM;   // attn_res lives in d_out second half

  char* p = (char*)d_ws;
  auto alloc = [&](size_t n) { char* r = p; p += (n + 255) & ~(size_t)255; return r; };
  f16*  nh   = (f16*)alloc((size_t)T_TOK*DIM*2);
  f16*  nl   = (f16*)alloc((size_t)T_TOK*DIM*2);
  float* qkvf = (float*)alloc((size_t)T_TOK*3072*4);
  f16*  H    = (f16*)qkvf;  // alias: qkvf dead after rope/split_v, H used in MoE
  f16*  qh   = (f16*)alloc((size_t)T_TOK*NQ*2);
  f16*  ql   = (f16*)alloc((size_t)T_TOK*NQ*2);
  f16*  kh   = (f16*)alloc((size_t)T_TOK*NKVD*2);
  f16*  kl   = (f16*)alloc((size_t)T_TOK*NKVD*2);
  f16*  vh   = (f16*)alloc((size_t)T_TOK*NKVD*2);
  f16*  vl   = (f16*)alloc((size_t)T_TOK*NKVD*2);
  f16*  oh   = (f16*)alloc((size_t)T_TOK*NQ*2);
  f16*  ol   = (f16*)alloc((size_t)T_TOK*NQ*2);
  f16*  n2   = (f16*)alloc((size_t)T_TOK*DIM*2);
  int*  topi = (int*)alloc(2*T_TOK*4);
  float* topw = (float*)alloc(2*T_TOK*4);
  int*  cnt  = (int*)alloc(64);
  int*  offs = (int*)alloc(64);
  int*  fill = (int*)alloc(64);
  int*  toks = (int*)alloc(2*T_TOK*4);
  float* wslot = (float*)alloc(2*T_TOK*4);

  k_rmsnorm1<<<T_TOK, 256, 0, stream>>>(hid, resi, ln1, resbuf, nh, nl);
  k_gemm_s3<0><<<dim3(16, 32), 256, 0, stream>>>(nh, nl, DIM, wq, NQ,   qkvf,        3072, DIM);
  k_gemm_s3<0><<<dim3(4, 32),  256, 0, stream>>>(nh, nl, DIM, wk, NKVD, qkvf + 2048, 3072, DIM);
  k_gemm_s3<0><<<dim3(4, 32),  256, 0, stream>>>(nh, nl, DIM, wv, NKVD, qkvf + 2560, 3072, DIM);
  k_rope<<<T_TOK, 256, 0, stream>>>(qkvf, cosb, sinb, qh, ql, kh, kl);
  k_split_v<<<1024, 256, 0, stream>>>(qkvf, vh, vl);
  k_attn<<<dim3(32, NHEAD, 2), 256, 0, stream>>>(qh, ql, kh, kl, vh, vl, oh, ol);
  k_gemm_s3<1><<<dim3(16, 32), 256, 0, stream>>>(oh, ol, NQ, wo, DIM, resbuf, DIM, NQ);
  k_rms2_router<<<T_TOK, 256, 0, stream>>>(resbuf, ln2, rw, n2, topi, topw);
  k_count<<<1, 256, 0, stream>>>(topi, cnt, offs, fill);
  k_scatter<<<32, 256, 0, stream>>>(topi, topw, offs, fill, toks, wslot);
  hipMemsetAsync(out1, 0, (size_t)T_TOK*DIM*4, stream);
  k_moe_up<<<dim3(11, 32, NEXP), 256, 0, stream>>>(n2, w1, w3, cnt, offs, toks, H);
  k_moe_down<<<dim3(16, 32, NEXP), 256, 0, stream>>>(H, w2, cnt, offs, toks, wslot, out1);
}